// Round 6
// baseline (376.069 us; speedup 1.0000x reference)
//
#include <hip/hip_runtime.h>

// HierarchicalLTI2: 32-layer cascade of 64-dim LTI blocks, T=8192.
// Per-layer FIR truncation at J=16 taps, each layer = GEMM (M=8192,N=64,K=1024)
// via implicit im2col, f16 MFMA fp32-acc.
// R8 = R7 with halo fix: halo start is (first phase-1 output row - 16) =
// t0-48 (NOT t0-64; R7 shifted all inputs by 16 rows -> absmax 32).
// 16-row tiles, grid 512 = 2 blocks/CU (8 waves/CU), phases S=4/3/2/1,
// halo 80 rows, LDS 48KB/block. castK folded into build_step s=3.

#define LYR 32
#define NO  64
#define TSEQ 8192
#define JT  16
#define KD  (JT*NO)              // 1024
#define PROWS (TSEQ+JT)          // 8208
#define PBUF ((size_t)PROWS*NO)  // 525312 elements (f16)
#define FD  4                    // fusion depth

typedef _Float16 h16;
typedef _Float16 h16x8 __attribute__((ext_vector_type(8)));
typedef float    f32x4 __attribute__((ext_vector_type(4)));

// ---- prep1: zero pads (all 33 buffers), cast u + C, seed K_0 (vectorized x8)
__global__ __launch_bounds__(256) void prep1(
    const float* __restrict__ u, const float* __restrict__ B0,
    const float* __restrict__ Bl, const float* __restrict__ Cst,
    h16* __restrict__ pall, h16* __restrict__ ccast, float* __restrict__ kf32)
{
    const int n_pad0 = JT*NO;            // 1024
    const int n_u    = TSEQ*NO;          // 524288
    const int n_c    = LYR*NO*NO;        // 131072
    const int n_k    = LYR*NO*NO;        // 131072
    const int n_zp   = 32*JT*NO;         // 32768 (pads of buffers 1..32)
    const int total8 = (n_pad0 + n_u + n_c + n_k + n_zp) >> 3;
    int idx8 = blockIdx.x*256 + threadIdx.x;
    const int4 zero4 = make_int4(0,0,0,0);
    for (; idx8 < total8; idx8 += gridDim.x*256) {
        int e = idx8 << 3;
        if (e < n_pad0) { *(int4*)&pall[e] = zero4; continue; }
        e -= n_pad0;
        if (e < n_u) {
            f32x4 f0 = *(const f32x4*)&u[e];
            f32x4 f1 = *(const f32x4*)&u[e+4];
            h16 ov[8];
            #pragma unroll
            for (int j = 0; j < 4; j++) { ov[j] = (h16)f0[j]; ov[4+j] = (h16)f1[j]; }
            *(int4*)&pall[n_pad0 + e] = *(int4*)&ov[0];
            continue;
        }
        e -= n_u;
        if (e < n_c) {
            f32x4 f0 = *(const f32x4*)&Cst[e];
            f32x4 f1 = *(const f32x4*)&Cst[e+4];
            h16 ov[8];
            #pragma unroll
            for (int j = 0; j < 4; j++) { ov[j] = (h16)f0[j]; ov[4+j] = (h16)f1[j]; }
            *(int4*)&ccast[e] = *(int4*)&ov[0];
            continue;
        }
        e -= n_c;
        if (e < n_k) {
            int i = e >> 12;
            int r = e & 4095;
            const float* src = (i == 0) ? &B0[r] : &Bl[e - 4096];
            float* dst = &kf32[((size_t)i*JT)*4096 + r];
            *(f32x4*)&dst[0] = *(const f32x4*)&src[0];
            *(f32x4*)&dst[4] = *(const f32x4*)&src[4];
            continue;
        }
        e -= n_k;
        int b = e >> 10;                 // buffer-1 index 0..31
        int off = e & 1023;
        *(int4*)&pall[(size_t)(b+1)*PBUF + off] = zero4;
    }
}

// ---- build_step: K_{h+q} = A^h * K_q ; A^{2h} = A^h * A^h (s=0..3) ---------
// s==3 additionally casts K_{8+q} (from acc) and K_q (from kf32) into kt,
// replacing the separate castK pass.
__global__ __launch_bounds__(256) void build_step(
    const float* __restrict__ A_stack, float* __restrict__ kf32,
    float* __restrict__ apow, h16* __restrict__ kt, int s)
{
    int h = 1 << s;
    int extra = (s < 3) ? 1 : 0;
    int slots = h + extra;
    int layer = blockIdx.x / slots;
    int q     = blockIdx.x % slots;
    const float* X = (s == 0) ? (A_stack + (size_t)layer*4096)
                              : (apow + ((size_t)layer*4 + (s-1))*4096);
    const float* Yop;
    float* Z;
    if (q < h) { Yop = kf32 + ((size_t)layer*JT + q)*4096;
                 Z   = kf32 + ((size_t)layer*JT + h + q)*4096; }
    else       { Yop = X;
                 Z   = apow + ((size_t)layer*4 + s)*4096; }

    __shared__ float lx[64*68];
    __shared__ float ly[64*68];
    int tid = threadIdx.x;
    for (int e = tid; e < 4096; e += 256) {
        int r = e >> 6, c = e & 63;
        lx[r*68 + c] = X[e];
        ly[r*68 + c] = Yop[e];
    }
    __syncthreads();
    int r0 = (tid >> 4) << 2;
    int c0 = (tid & 15) << 2;
    float acc[4][4] = {};
    for (int k = 0; k < 64; k++) {
        float a0 = lx[(r0+0)*68 + k];
        float a1 = lx[(r0+1)*68 + k];
        float a2 = lx[(r0+2)*68 + k];
        float a3 = lx[(r0+3)*68 + k];
        f32x4 bv = *(const f32x4*)&ly[k*68 + c0];
        #pragma unroll
        for (int j = 0; j < 4; j++) {
            acc[0][j] += a0*bv[j]; acc[1][j] += a1*bv[j];
            acc[2][j] += a2*bv[j]; acc[3][j] += a3*bv[j];
        }
    }
    if (s < 3) {
        #pragma unroll
        for (int i2 = 0; i2 < 4; i2++) {
            f32x4 o; o[0]=acc[i2][0]; o[1]=acc[i2][1]; o[2]=acc[i2][2]; o[3]=acc[i2][3];
            *(f32x4*)&Z[(size_t)(r0+i2)*64 + c0] = o;
        }
    } else {
        // Z = K_{8+q}: cast directly from registers into kt.
        // kt[i][n][jp*64+m], jp = 15-j.  j = 8+q -> jp = 7-q.
        size_t kb = (size_t)layer*65536 + (size_t)(7 - q)*64;
        #pragma unroll
        for (int i2 = 0; i2 < 4; i2++) {
            h16 o4[4];
            #pragma unroll
            for (int j = 0; j < 4; j++) o4[j] = (h16)acc[i2][j];
            *(int2*)&kt[kb + (size_t)(r0+i2)*1024 + c0] = *(int2*)&o4[0];
        }
        // also cast K_q (j = q -> jp = 15-q) from kf32.
        const float* Ksrc = kf32 + ((size_t)layer*JT + q)*4096;
        size_t kb2 = (size_t)layer*65536 + (size_t)(15 - q)*64;
        for (int g = tid; g < 1024; g += 256) {
            int n  = g >> 4;
            int m4 = (g & 15) << 2;
            f32x4 f = *(const f32x4*)&Ksrc[(size_t)n*64 + m4];
            h16 o4[4];
            #pragma unroll
            for (int t = 0; t < 4; t++) o4[t] = (h16)f[t];
            *(int2*)&kt[kb2 + (size_t)n*1024 + m4] = *(int2*)&o4[0];
        }
    }
}

// ---- fused-stage phase: GEMM M=16*S, N=64, K=1024, split-K4 ----------------
// inb: LDS input, stride 72, rows >= 16*(S+1). outb: LDS output (stride 72) or
// null for last phase. gout: global base at padded row (t0+16), pitch 64.
// w0: local row where the canonical 16-row window starts.
// B-frags (global kt) prefetched 4 half-steps deep; A-frags (LDS) 2 deep.
template<int S>
__device__ __forceinline__ void phase_body(
    const h16* inb, h16* outb, const h16* __restrict__ kb,
    h16* __restrict__ gout, const int w0, float* red, const int tid)
{
    const int wv = tid >> 6, lane = tid & 63, r = lane & 15, q = lane >> 4;
    const h16* abase = inb + (r + wv*4)*72 + q*8;
    const h16* bbase = kb + (size_t)r*KD + wv*256 + q*8;
#define LDA(s, ls) (*(const h16x8*)(abase + ((s)*16 + ((ls)>>1))*72 + ((ls)&1)*32))
#define LDB(c, ls) (*(const h16x8*)(bbase + (c)*(16*KD) + (ls)*32))
    f32x4 acc[S][4] = {};
    h16x8 a[2][S], b[4][4];
    #pragma unroll
    for (int ls = 0; ls < 2; ls++)
        #pragma unroll
        for (int s = 0; s < S; s++) a[ls][s] = LDA(s, ls);
    #pragma unroll
    for (int ls = 0; ls < 4; ls++)
        #pragma unroll
        for (int c = 0; c < 4; c++) b[ls][c] = LDB(c, ls);
    #pragma unroll
    for (int ls = 0; ls < 8; ls++) {
        h16x8 ca[S], cb[4];
        #pragma unroll
        for (int s = 0; s < S; s++) ca[s] = a[ls&1][s];
        #pragma unroll
        for (int c = 0; c < 4; c++) cb[c] = b[ls&3][c];
        if (ls < 6) {
            #pragma unroll
            for (int s = 0; s < S; s++) a[ls&1][s] = LDA(s, ls+2);
        }
        if (ls < 4) {
            #pragma unroll
            for (int c = 0; c < 4; c++) b[ls&3][c] = LDB(c, ls+4);
        }
        #pragma unroll
        for (int s = 0; s < S; s++)
            #pragma unroll
            for (int c = 0; c < 4; c++)
                acc[s][c] = __builtin_amdgcn_mfma_f32_16x16x32_f16(ca[s], cb[c], acc[s][c], 0,0,0);
    }
#undef LDA
#undef LDB
    // split-K reduction + combine, chunked over 3 row-tiles (red = 2 x 48x68 f32)
    const int cb2 = (tid & 7) << 3;
    #pragma unroll
    for (int ch = 0; ch < (S+2)/3; ch++) {
        const int sbase = ch*3;
        const int nt = (S - sbase) < 3 ? (S - sbase) : 3;
        __syncthreads();                 // red free (prev chunk / prev phase done)
        if (wv >= 2) {
            float* myred = red + (size_t)(wv-2)*(48*68);
            #pragma unroll
            for (int s2 = 0; s2 < 3; s2++) if (s2 < nt)
                #pragma unroll
                for (int c = 0; c < 4; c++)
                    #pragma unroll
                    for (int g = 0; g < 4; g++)
                        myred[(s2*16 + q*4 + g)*68 + c*16 + r] = acc[sbase+s2][c][g];
        }
        __syncthreads();
        if (wv < 2) {
            float* myred = red + (size_t)wv*(48*68);
            #pragma unroll
            for (int s2 = 0; s2 < 3; s2++) if (s2 < nt)
                #pragma unroll
                for (int c = 0; c < 4; c++)
                    #pragma unroll
                    for (int g = 0; g < 4; g++)
                        myred[(s2*16 + q*4 + g)*68 + c*16 + r] += acc[sbase+s2][c][g];
        }
        __syncthreads();
        for (int w = tid >> 3; w < nt*16; w += 32) {
            f32x4 u0 = *(const f32x4*)&red[w*68 + cb2];
            f32x4 u1 = *(const f32x4*)&red[w*68 + cb2 + 4];
            f32x4 v0 = *(const f32x4*)&red[48*68 + w*68 + cb2];
            f32x4 v1 = *(const f32x4*)&red[48*68 + w*68 + cb2 + 4];
            u0 += v0; u1 += v1;
            h16 ov[8];
            #pragma unroll
            for (int j = 0; j < 4; j++) { ov[j] = (h16)u0[j]; ov[4+j] = (h16)u1[j]; }
            const int W = sbase*16 + w;          // global-phase row
            if (outb) *(int4*)&outb[W*72 + cb2] = *(int4*)&ov[0];
            const unsigned wrel = (unsigned)(W - w0);
            if (wrel < 16u) *(int4*)&gout[(size_t)wrel*64 + cb2] = *(int4*)&ov[0];
        }
    }
    __syncthreads();                     // outb ready for next phase
}

// ---- stage4: 4 fused cascade layers, one 16-row output tile per block ------
// grid 512 = 2 blocks/CU: 8 waves/CU for latency hiding.
__global__ __launch_bounds__(256, 2) void stage4(
    h16* pall, const h16* __restrict__ kt, int i0)
{
    __shared__ __align__(16) h16   bufA[80*72];      // 11,520 B
    __shared__ __align__(16) h16   bufB[80*72];      // 11,520 B
    __shared__ __align__(16) float red[2*48*68];     // 26,112 B  (total 48 KB)
    const int tid = threadIdx.x;
    const size_t t0 = (size_t)blockIdx.x * 16;

    // stage input halo: 80 rows = padded rows t0-48 .. t0+31 of buffer i0.
    // (halo start = first phase-1 output row (t0-32) minus 16 taps.)
    const h16* pin = pall + (size_t)i0*PBUF;
    for (int e = tid; e < 80*8; e += 256) {
        int rr = e >> 3, cc = e & 7;
        long g = (long)t0 - 48 + rr;
        int4 v = make_int4(0,0,0,0);
        if (g >= 0) v = *(const int4*)&pin[(size_t)g*64 + cc*8];
        *(int4*)&bufA[rr*72 + cc*8] = v;
    }
    __syncthreads();

    h16* g1 = pall + (size_t)(i0+1)*PBUF + (JT + t0)*64;
    h16* g2 = pall + (size_t)(i0+2)*PBUF + (JT + t0)*64;
    h16* g3 = pall + (size_t)(i0+3)*PBUF + (JT + t0)*64;
    h16* g4 = pall + (size_t)(i0+4)*PBUF + (JT + t0)*64;
    const h16* k1 = kt + (size_t)(i0+0)*NO*KD;
    const h16* k2 = kt + (size_t)(i0+1)*NO*KD;
    const h16* k3 = kt + (size_t)(i0+2)*NO*KD;
    const h16* k4 = kt + (size_t)(i0+3)*NO*KD;

    phase_body<4>(bufA, bufB, k1, g1, 48, red, tid);   // layer i0+1: M=64
    phase_body<3>(bufB, bufA, k2, g2, 32, red, tid);   // layer i0+2: M=48
    phase_body<2>(bufA, bufB, k3, g3, 16, red, tid);   // layer i0+3: M=32
    phase_body<1>(bufB, (h16*)0, k4, g4, 0, red, tid); // layer i0+4: M=16
}

// ---- y_final: Y = sum_i X^(i) C_i^T, 16-row tiles, split-K4, 4-deep pf -----
__global__ __launch_bounds__(256, 2) void y_final(
    const h16* __restrict__ pall, const h16* __restrict__ ccast,
    float* __restrict__ out)
{
    __shared__ __align__(16) float red[2*16*68];
    int tid = threadIdx.x;
    size_t t0 = (size_t)blockIdx.x * 16;
    int wv = tid >> 6, lane = tid & 63, r = lane & 15, q = lane >> 4;
    // wave wv owns layers i in [wv*8, wv*8+8): 16 half-steps of 32 K-elems
    const h16* abase = pall + (size_t)(wv*8 + 1)*PBUF + (JT + t0 + r)*64 + q*8;
    const h16* bbase = ccast + (size_t)(wv*8)*4096 + (size_t)r*64 + q*8;
#define LDA2(ls) (*(const h16x8*)(abase + (size_t)((ls)>>1)*PBUF + ((ls)&1)*32))
#define LDB2(c, ls) (*(const h16x8*)(bbase + ((ls)>>1)*4096 + (c)*(16*64) + ((ls)&1)*32))
    f32x4 acc[4] = {};
    h16x8 a[4], b[4][4];
    #pragma unroll
    for (int ls = 0; ls < 4; ls++) {
        a[ls] = LDA2(ls);
        #pragma unroll
        for (int c = 0; c < 4; c++) b[ls][c] = LDB2(c, ls);
    }
    #pragma unroll
    for (int ls = 0; ls < 16; ls++) {
        h16x8 ca = a[ls&3], cb[4];
        #pragma unroll
        for (int c = 0; c < 4; c++) cb[c] = b[ls&3][c];
        if (ls < 12) {
            a[ls&3] = LDA2(ls+4);
            #pragma unroll
            for (int c = 0; c < 4; c++) b[ls&3][c] = LDB2(c, ls+4);
        }
        #pragma unroll
        for (int c = 0; c < 4; c++)
            acc[c] = __builtin_amdgcn_mfma_f32_16x16x32_f16(ca, cb[c], acc[c], 0,0,0);
    }
#undef LDA2
#undef LDB2
    if (wv >= 2) {
        float* myred = red + (size_t)(wv-2)*(16*68);
        #pragma unroll
        for (int c = 0; c < 4; c++)
            #pragma unroll
            for (int g = 0; g < 4; g++)
                myred[(q*4 + g)*68 + c*16 + r] = acc[c][g];
    }
    __syncthreads();
    if (wv < 2) {
        float* myred = red + (size_t)wv*(16*68);
        #pragma unroll
        for (int c = 0; c < 4; c++)
            #pragma unroll
            for (int g = 0; g < 4; g++)
                myred[(q*4 + g)*68 + c*16 + r] += acc[c][g];
    }
    __syncthreads();
    int orow = tid >> 4, c4 = (tid & 15) << 2;
    f32x4 u0 = *(const f32x4*)&red[orow*68 + c4];
    f32x4 v0 = *(const f32x4*)&red[16*68 + orow*68 + c4];
    u0 += v0;
    *(f32x4*)&out[(t0 + orow)*64 + c4] = u0;
}

extern "C" void kernel_launch(void* const* d_in, const int* in_sizes, int n_in,
                              void* d_out, int out_size, void* d_ws, size_t ws_size,
                              hipStream_t stream)
{
    const float* u   = (const float*)d_in[0];
    const float* Ast = (const float*)d_in[1];
    const float* B0  = (const float*)d_in[2];
    const float* Bl  = (const float*)d_in[3];
    const float* Cst = (const float*)d_in[4];
    float* out = (float*)d_out;
    (void)in_sizes; (void)n_in; (void)out_size; (void)ws_size;

    char* ws = (char*)d_ws;
    const size_t PBUF_BYTES = PBUF*sizeof(h16);            // 1,050,624
    h16*   pall  = (h16*)ws;                               // 33 buffers
    h16*   ccast = (h16*)(ws + 33*PBUF_BYTES);             // 256 KiB
    h16*   kt    = (h16*)(ws + 33*PBUF_BYTES + 262144);    // 4 MiB
    float* kf32  = (float*)(ws + 33*PBUF_BYTES + 262144 + 4194304);   // 8 MiB
    float* apow  = (float*)(ws + 33*PBUF_BYTES + 262144 + 4194304 + 8388608); // 2 MiB

    prep1<<<512, 256, 0, stream>>>(u, B0, Bl, Cst, pall, ccast, kf32);
    for (int s = 0; s < 4; s++) {
        int h = 1 << s;
        int grid = 32*(h + (s < 3 ? 1 : 0));
        build_step<<<grid, 256, 0, stream>>>(Ast, kf32, apow, kt, s);
    }
    for (int i = 0; i < LYR; i += FD) {
        stage4<<<TSEQ/16, 256, 0, stream>>>(pall, kt, i);
    }
    y_final<<<TSEQ/16, 256, 0, stream>>>(pall, ccast, out);
}

// Round 7
// 317.854 us; speedup vs baseline: 1.1831x; 1.1831x over previous
//
#include <hip/hip_runtime.h>

// HierarchicalLTI2: 32-layer cascade of 64-dim LTI blocks, T=8192.
// Per-layer FIR truncation at J=16 taps, each layer = GEMM (M=8192,N=64,K=1024)
// via implicit im2col, f16 MFMA fp32-acc.
// R9: launch overhead measured ~4.8us (ladder fit R0/R5/R6/R8). Changes vs R6:
//  (1) prep+build+castK merged into ONE launch: blocks 0-31 build their layer's
//      K chain sequentially in LDS (K_j = A*K_{j-1}, f32) casting slices
//      straight into kt; blocks 32-543 do the prep zero/cast work.
//  (2) FD 4->2: per-32-row work 112->80 tile-units (fusion adds recompute;
//      with L~4.8us the optimum shifts down). phase_body identical to R6.
// R8 lesson: 16-row tiles / 2 blocks/CU regressed (+43% work, 2x kt traffic).

#define LYR 32
#define NO  64
#define TSEQ 8192
#define JT  16
#define KD  (JT*NO)              // 1024
#define PROWS (TSEQ+JT)          // 8208
#define PBUF ((size_t)PROWS*NO)  // 525312 elements (f16)

typedef _Float16 h16;
typedef _Float16 h16x8 __attribute__((ext_vector_type(8)));
typedef float    f32x4 __attribute__((ext_vector_type(4)));

// ---- prep_build: one launch replacing prep1 + 4x build_step + castK --------
// blocks 0..31: build layer b's K chain: K_0 = (b? Bl[b-1] : B0);
//   K_j = A_b * K_{j-1}, j=1..15 (f32 in LDS), each slice cast to kt
//   kt[b][n][(15-j)*64 + m].
// blocks 32..543: zero pads (33 buffers), cast u + C.
__global__ __launch_bounds__(256) void prep_build(
    const float* __restrict__ u, const float* __restrict__ B0,
    const float* __restrict__ Bl, const float* __restrict__ Cst,
    const float* __restrict__ Ast,
    h16* __restrict__ pall, h16* __restrict__ ccast, h16* __restrict__ kt)
{
    __shared__ float sm[3*64*68];            // 52,224 B
    const int tid = threadIdx.x;

    if (blockIdx.x < 32) {
        const int layer = blockIdx.x;
        float* la = sm;                      // A_layer
        float* kc = sm + 64*68;              // K_cur
        float* kn = sm + 2*64*68;            // K_next
        const float* k0 = (layer == 0) ? B0 : (Bl + (size_t)(layer-1)*4096);
        const float* Aw = Ast + (size_t)layer*4096;
        for (int e = tid; e < 4096; e += 256) {
            int r = e >> 6, c = e & 63;
            kc[r*68 + c] = k0[e];
            la[r*68 + c] = Aw[e];
        }
        __syncthreads();
        // write jp=15 slice (K_0)
        {
            size_t kb = (size_t)layer*65536 + 15*64;
            for (int e2 = tid; e2 < 1024; e2 += 256) {
                int n = e2 >> 4, c4 = (e2 & 15) << 2;
                h16 o4[4];
                #pragma unroll
                for (int t = 0; t < 4; t++) o4[t] = (h16)kc[n*68 + c4 + t];
                *(int2*)&kt[kb + (size_t)n*1024 + c4] = *(int2*)&o4[0];
            }
        }
        const int r0 = (tid >> 4) << 2;
        const int c0 = (tid & 15) << 2;
        for (int j = 1; j <= 15; j++) {
            float acc[4][4] = {};
            for (int k = 0; k < 64; k++) {
                float a0 = la[(r0+0)*68 + k];
                float a1 = la[(r0+1)*68 + k];
                float a2 = la[(r0+2)*68 + k];
                float a3 = la[(r0+3)*68 + k];
                f32x4 bv = *(const f32x4*)&kc[k*68 + c0];
                #pragma unroll
                for (int jj = 0; jj < 4; jj++) {
                    acc[0][jj] += a0*bv[jj]; acc[1][jj] += a1*bv[jj];
                    acc[2][jj] += a2*bv[jj]; acc[3][jj] += a3*bv[jj];
                }
            }
            // store K_j to LDS (for next iter) and cast slice jp=15-j to kt
            size_t kb = (size_t)layer*65536 + (size_t)(15 - j)*64;
            #pragma unroll
            for (int i2 = 0; i2 < 4; i2++) {
                f32x4 o; o[0]=acc[i2][0]; o[1]=acc[i2][1]; o[2]=acc[i2][2]; o[3]=acc[i2][3];
                *(f32x4*)&kn[(r0+i2)*68 + c0] = o;
                h16 o4[4];
                #pragma unroll
                for (int t = 0; t < 4; t++) o4[t] = (h16)acc[i2][t];
                *(int2*)&kt[kb + (size_t)(r0+i2)*1024 + c0] = *(int2*)&o4[0];
            }
            __syncthreads();
            float* tmp = kc; kc = kn; kn = tmp;
        }
        return;
    }

    // ---- prep section (512 blocks) ----
    const int n_pad0 = JT*NO;            // 1024
    const int n_u    = TSEQ*NO;          // 524288
    const int n_c    = LYR*NO*NO;        // 131072
    const int n_zp   = 32*JT*NO;         // 32768 (pads of buffers 1..32)
    const int total8 = (n_pad0 + n_u + n_c + n_zp) >> 3;   // 86,144
    int idx8 = (blockIdx.x - 32)*256 + tid;
    const int4 zero4 = make_int4(0,0,0,0);
    for (; idx8 < total8; idx8 += 512*256) {
        int e = idx8 << 3;
        if (e < n_pad0) { *(int4*)&pall[e] = zero4; continue; }
        e -= n_pad0;
        if (e < n_u) {
            f32x4 f0 = *(const f32x4*)&u[e];
            f32x4 f1 = *(const f32x4*)&u[e+4];
            h16 ov[8];
            #pragma unroll
            for (int j = 0; j < 4; j++) { ov[j] = (h16)f0[j]; ov[4+j] = (h16)f1[j]; }
            *(int4*)&pall[n_pad0 + e] = *(int4*)&ov[0];
            continue;
        }
        e -= n_u;
        if (e < n_c) {
            f32x4 f0 = *(const f32x4*)&Cst[e];
            f32x4 f1 = *(const f32x4*)&Cst[e+4];
            h16 ov[8];
            #pragma unroll
            for (int j = 0; j < 4; j++) { ov[j] = (h16)f0[j]; ov[4+j] = (h16)f1[j]; }
            *(int4*)&ccast[e] = *(int4*)&ov[0];
            continue;
        }
        e -= n_c;
        int b = e >> 10;                 // buffer-1 index 0..31
        int off = e & 1023;
        *(int4*)&pall[(size_t)(b+1)*PBUF + off] = zero4;
    }
}

// ---- fused-stage phase: GEMM M=16*S, N=64, K=1024, split-K4 ----------------
// (verbatim from verified R6)
template<int S>
__device__ __forceinline__ void phase_body(
    const h16* inb, h16* outb, const h16* __restrict__ kb,
    h16* __restrict__ gout, const int w0, float* red, const int tid)
{
    const int wv = tid >> 6, lane = tid & 63, r = lane & 15, q = lane >> 4;
    const h16* abase = inb + (r + wv*4)*72 + q*8;
    const h16* bbase = kb + (size_t)r*KD + wv*256 + q*8;
#define LDA(s, ls) (*(const h16x8*)(abase + ((s)*16 + ((ls)>>1))*72 + ((ls)&1)*32))
#define LDB(c, ls) (*(const h16x8*)(bbase + (c)*(16*KD) + (ls)*32))
    f32x4 acc[S][4] = {};
    h16x8 a[2][S], b[4][4];
    #pragma unroll
    for (int ls = 0; ls < 2; ls++)
        #pragma unroll
        for (int s = 0; s < S; s++) a[ls][s] = LDA(s, ls);
    #pragma unroll
    for (int ls = 0; ls < 4; ls++)
        #pragma unroll
        for (int c = 0; c < 4; c++) b[ls][c] = LDB(c, ls);
    #pragma unroll
    for (int ls = 0; ls < 8; ls++) {
        h16x8 ca[S], cb[4];
        #pragma unroll
        for (int s = 0; s < S; s++) ca[s] = a[ls&1][s];
        #pragma unroll
        for (int c = 0; c < 4; c++) cb[c] = b[ls&3][c];
        if (ls < 6) {
            #pragma unroll
            for (int s = 0; s < S; s++) a[ls&1][s] = LDA(s, ls+2);
        }
        if (ls < 4) {
            #pragma unroll
            for (int c = 0; c < 4; c++) b[ls&3][c] = LDB(c, ls+4);
        }
        #pragma unroll
        for (int s = 0; s < S; s++)
            #pragma unroll
            for (int c = 0; c < 4; c++)
                acc[s][c] = __builtin_amdgcn_mfma_f32_16x16x32_f16(ca[s], cb[c], acc[s][c], 0,0,0);
    }
#undef LDA
#undef LDB
    // split-K reduction + combine, chunked over 3 row-tiles (red = 2 x 48x68 f32)
    const int cb2 = (tid & 7) << 3;
    #pragma unroll
    for (int ch = 0; ch < (S+2)/3; ch++) {
        const int sbase = ch*3;
        const int nt = (S - sbase) < 3 ? (S - sbase) : 3;
        __syncthreads();                 // red free (prev chunk / prev phase done)
        if (wv >= 2) {
            float* myred = red + (size_t)(wv-2)*(48*68);
            #pragma unroll
            for (int s2 = 0; s2 < 3; s2++) if (s2 < nt)
                #pragma unroll
                for (int c = 0; c < 4; c++)
                    #pragma unroll
                    for (int g = 0; g < 4; g++)
                        myred[(s2*16 + q*4 + g)*68 + c*16 + r] = acc[sbase+s2][c][g];
        }
        __syncthreads();
        if (wv < 2) {
            float* myred = red + (size_t)wv*(48*68);
            #pragma unroll
            for (int s2 = 0; s2 < 3; s2++) if (s2 < nt)
                #pragma unroll
                for (int c = 0; c < 4; c++)
                    #pragma unroll
                    for (int g = 0; g < 4; g++)
                        myred[(s2*16 + q*4 + g)*68 + c*16 + r] += acc[sbase+s2][c][g];
        }
        __syncthreads();
        for (int w = tid >> 3; w < nt*16; w += 32) {
            f32x4 u0 = *(const f32x4*)&red[w*68 + cb2];
            f32x4 u1 = *(const f32x4*)&red[w*68 + cb2 + 4];
            f32x4 v0 = *(const f32x4*)&red[48*68 + w*68 + cb2];
            f32x4 v1 = *(const f32x4*)&red[48*68 + w*68 + cb2 + 4];
            u0 += v0; u1 += v1;
            h16 ov[8];
            #pragma unroll
            for (int j = 0; j < 4; j++) { ov[j] = (h16)u0[j]; ov[4+j] = (h16)u1[j]; }
            const int W = sbase*16 + w;          // global-phase row
            if (outb) *(int4*)&outb[W*72 + cb2] = *(int4*)&ov[0];
            const unsigned wrel = (unsigned)(W - w0);
            if (wrel < 32u) *(int4*)&gout[(size_t)wrel*64 + cb2] = *(int4*)&ov[0];
        }
    }
    __syncthreads();                     // outb ready for next phase
}

// ---- stage2: 2 fused cascade layers, one 32-row output tile per block ------
// halo 64 rows (t0-16 .. t0+47); phases S=3 (w0=16), S=2 (w0=0).
__global__ __launch_bounds__(256) void stage2(
    h16* pall, const h16* __restrict__ kt, int i0)
{
    __shared__ __align__(16) h16   bufA[64*72];      //  9,216 B
    __shared__ __align__(16) h16   bufB[48*72];      //  6,912 B
    __shared__ __align__(16) float red[2*48*68];     // 26,112 B
    const int tid = threadIdx.x;
    const size_t t0 = (size_t)blockIdx.x * 32;

    // halo: 64 rows = padded rows t0-16 .. t0+47 of buffer i0
    // (phase-1 first output row is t0, which needs inputs from t0-16.)
    const h16* pin = pall + (size_t)i0*PBUF;
    for (int e = tid; e < 64*8; e += 256) {
        int rr = e >> 3, cc = e & 7;
        long g = (long)t0 - 16 + rr;
        int4 v = make_int4(0,0,0,0);
        if (g >= 0) v = *(const int4*)&pin[(size_t)g*64 + cc*8];
        *(int4*)&bufA[rr*72 + cc*8] = v;
    }
    __syncthreads();

    h16* g1 = pall + (size_t)(i0+1)*PBUF + (JT + t0)*64;
    h16* g2 = pall + (size_t)(i0+2)*PBUF + (JT + t0)*64;
    const h16* k1 = kt + (size_t)(i0+0)*NO*KD;
    const h16* k2 = kt + (size_t)(i0+1)*NO*KD;

    phase_body<3>(bufA, bufB, k1, g1, 16, red, tid);   // layer i0+1: M=48
    phase_body<2>(bufB, (h16*)0, k2, g2, 0, red, tid); // layer i0+2: M=32
}

// ---- y_final: Y = sum_i X^(i) C_i^T, 32-row tiles, split-K4, 4-deep pf -----
// (verbatim from verified R6)
__global__ __launch_bounds__(256, 2) void y_final(
    const h16* __restrict__ pall, const h16* __restrict__ ccast,
    float* __restrict__ out)
{
    __shared__ __align__(16) float red[2*32*68];
    int tid = threadIdx.x;
    size_t t0 = (size_t)blockIdx.x * 32;
    int wv = tid >> 6, lane = tid & 63, r = lane & 15, q = lane >> 4;
    const h16* abase = pall + (size_t)(wv*8 + 1)*PBUF + (JT + t0 + r)*64 + q*8;
    const h16* bbase = ccast + (size_t)(wv*8)*4096 + (size_t)r*64 + q*8;
#define LDA2(s, ls) (*(const h16x8*)(abase + (size_t)((ls)>>1)*PBUF + (s)*(16*64) + ((ls)&1)*32))
#define LDB2(c, ls) (*(const h16x8*)(bbase + ((ls)>>1)*4096 + (c)*(16*64) + ((ls)&1)*32))
    f32x4 acc[2][4] = {};
    h16x8 a[4][2], b[4][4];
    #pragma unroll
    for (int ls = 0; ls < 4; ls++) {
        #pragma unroll
        for (int s = 0; s < 2; s++) a[ls][s] = LDA2(s, ls);
        #pragma unroll
        for (int c = 0; c < 4; c++) b[ls][c] = LDB2(c, ls);
    }
    #pragma unroll
    for (int ls = 0; ls < 16; ls++) {
        h16x8 ca[2], cb[4];
        #pragma unroll
        for (int s = 0; s < 2; s++) ca[s] = a[ls&3][s];
        #pragma unroll
        for (int c = 0; c < 4; c++) cb[c] = b[ls&3][c];
        if (ls < 12) {
            #pragma unroll
            for (int s = 0; s < 2; s++) a[ls&3][s] = LDA2(s, ls+4);
            #pragma unroll
            for (int c = 0; c < 4; c++) b[ls&3][c] = LDB2(c, ls+4);
        }
        #pragma unroll
        for (int s = 0; s < 2; s++)
            #pragma unroll
            for (int c = 0; c < 4; c++)
                acc[s][c] = __builtin_amdgcn_mfma_f32_16x16x32_f16(ca[s], cb[c], acc[s][c], 0,0,0);
    }
#undef LDA2
#undef LDB2
    if (wv >= 2) {
        float* myred = red + (size_t)(wv-2)*(32*68);
        #pragma unroll
        for (int s = 0; s < 2; s++)
            #pragma unroll
            for (int c = 0; c < 4; c++)
                #pragma unroll
                for (int g = 0; g < 4; g++)
                    myred[(s*16 + q*4 + g)*68 + c*16 + r] = acc[s][c][g];
    }
    __syncthreads();
    if (wv < 2) {
        float* myred = red + (size_t)wv*(32*68);
        #pragma unroll
        for (int s = 0; s < 2; s++)
            #pragma unroll
            for (int c = 0; c < 4; c++)
                #pragma unroll
                for (int g = 0; g < 4; g++)
                    myred[(s*16 + q*4 + g)*68 + c*16 + r] += acc[s][c][g];
    }
    __syncthreads();
    int orow = tid >> 3, cb2 = (tid & 7) << 3;
    f32x4 u0 = *(const f32x4*)&red[orow*68 + cb2];
    f32x4 u1 = *(const f32x4*)&red[orow*68 + cb2 + 4];
    f32x4 v0 = *(const f32x4*)&red[32*68 + orow*68 + cb2];
    f32x4 v1 = *(const f32x4*)&red[32*68 + orow*68 + cb2 + 4];
    u0 += v0; u1 += v1;
    size_t obase = (t0 + orow)*64 + cb2;
    *(f32x4*)&out[obase]     = u0;
    *(f32x4*)&out[obase + 4] = u1;
}

extern "C" void kernel_launch(void* const* d_in, const int* in_sizes, int n_in,
                              void* d_out, int out_size, void* d_ws, size_t ws_size,
                              hipStream_t stream)
{
    const float* u   = (const float*)d_in[0];
    const float* Ast = (const float*)d_in[1];
    const float* B0  = (const float*)d_in[2];
    const float* Bl  = (const float*)d_in[3];
    const float* Cst = (const float*)d_in[4];
    float* out = (float*)d_out;
    (void)in_sizes; (void)n_in; (void)out_size; (void)ws_size;

    char* ws = (char*)d_ws;
    const size_t PBUF_BYTES = PBUF*sizeof(h16);            // 1,050,624
    h16*   pall  = (h16*)ws;                               // 33 buffers
    h16*   ccast = (h16*)(ws + 33*PBUF_BYTES);             // 256 KiB
    h16*   kt    = (h16*)(ws + 33*PBUF_BYTES + 262144);    // 4 MiB

    prep_build<<<544, 256, 0, stream>>>(u, B0, Bl, Cst, Ast, pall, ccast, kt);
    for (int i = 0; i < LYR; i += 2) {
        stage2<<<TSEQ/32, 256, 0, stream>>>(pall, kt, i);
    }
    y_final<<<TSEQ/32, 256, 0, stream>>>(pall, ccast, out);
}